// Round 10
// baseline (1637.103 us; speedup 1.0000x reference)
//
#include <hip/hip_runtime.h>
#include <math.h>

#define NTAU 82
#define TMIN 28
#define S_TOT 5617
#define TF 6000
#define BATCH 4
#define WMAX 28
#define AP 84            // A/fb row pitch: 82 + 2 pad; rows 336B = 21*16B aligned
#define NTHREADS 1024
#define NCHUNK 215
#define CHUNK_F (WMAX * AP)   // 2352 floats per chunk of A-history

// ws layout (float offsets)
#define TRANS_OFF 0            // 82*82
#define BLP_OFF   8192         // 4*6000
#define NBLP_OFF  32768        // 4*6000
#define AH_OFF    57344        // 4 * 215 * 2352 (chunk-major A history)

typedef float v2f __attribute__((ext_vector_type(2)));

__device__ __forceinline__ int first_of(int b) { return b * (55 + b) / 2; }
__device__ __forceinline__ int nf_of(int b)    { return b * (b - 1) / 2; }

__device__ __forceinline__ float logsig(float x) {
    return -(fmaxf(-x, 0.0f) + log1pf(expf(-fabsf(x))));
}

// ---------------- setup kernel 1: trans_log in fp64, cast to fp32 -------------
__global__ void k_trans(float* __restrict__ ws) {
    int i = blockIdx.x;
    int j = threadIdx.x;
    __shared__ double sh[128];
    double raw = 0.0, e = 0.0;
    double ti = 28.0 + (double)i;
    if (j < NTAU) {
        double tj = 28.0 + (double)j;
        raw = -100.0 * fabs(tj / ti - 1.0);
        e = exp(raw);
    }
    sh[j] = e;
    __syncthreads();
    for (int st = 64; st > 0; st >>= 1) {
        if (j < st) sh[j] += sh[j + st];
        __syncthreads();
    }
    double lse = log(sh[0]);
    if (j < NTAU) ws[TRANS_OFF + i * NTAU + j] = (float)(raw - lse);
}

// ---------------- setup kernel 2: emissions + zero output ---------------------
__global__ void k_emis(const float* __restrict__ logit, float* __restrict__ ws,
                       float* __restrict__ out) {
    int idx = blockIdx.x * blockDim.x + threadIdx.x;
    if (idx < BATCH * TF) {
        float x = logit[idx];
        ws[BLP_OFF + idx]  = logsig(x);
        ws[NBLP_OFF + idx] = logsig(-x);
        out[idx] = 0.0f;
    }
}

// ---------------- main kernel: chunked Viterbi + backtrace --------------------
// r9 base; ONLY change: prefix/suffix loops -> fully-unrolled cndmask adds on
// the register window nbr[] (no LDS reads / no runtime-trip loop latency).
__global__ __attribute__((amdgpu_flat_work_group_size(NTHREADS, NTHREADS),
                          amdgpu_waves_per_eu(4, 4),
                          amdgpu_num_vgpr(128)))
void k_viterbi(const float* __restrict__ logit,
               const float* __restrict__ transg,
               const float* __restrict__ blp_all,
               const float* __restrict__ nblp_all,
               float* __restrict__ Ah_all,
               float* __restrict__ out) {
    const int tid = threadIdx.x;
    const int b = blockIdx.x;

    const float* blp  = blp_all  + b * TF;
    const float* nblp = nblp_all + b * TF;
    float* Ah = Ah_all + (size_t)b * (NCHUNK * CHUNK_F);

    __shared__ float V[5632];                       // slot values, idx = first_of(b)+r
    __shared__ __align__(16) float A_lds[CHUNK_F];  // captures (prev_last) [tt][i]
    __shared__ __align__(16) float fb[CHUNK_F];     // from_beat [tt][j]
    __shared__ __align__(16) float win_nb[4][WMAX]; // quad-buffered emission windows
    __shared__ __align__(16) float win_b[4][WMAX];
    __shared__ float wv[16];
    __shared__ int   wi[16];

    // ---- ph2 mapping (r3-proven): quad lanes = iseg; jp = j-pair; tg = tl-group
    const int iseg = tid & 3;
    const int jp   = (tid >> 2) % 41;     // j-pair, j0 = 2*jp (0..80)
    const int tg   = tid / 164;           // 0..6 (quads never straddle: 164%4==0)
    const bool p2act = (tid < 984);       // 4*41*6
    const int i0 = iseg * 20;             // 20/20/20/22 split; 16B-aligned offsets
    const int j0 = jp * 2;

    // trans columns in registers: tr0/tr1[k] = trans[i0+k][j0 / j0+1]
    float tr0[22], tr1[22];
#pragma unroll
    for (int k = 0; k < 22; ++k) { tr0[k] = -1.0e30f; tr1[k] = -1.0e30f; }
    if (p2act) {
        const int icnt = (iseg == 3) ? 22 : 20;
#pragma unroll
        for (int k = 0; k < 22; ++k) {
            if (k < icnt) {
                tr0[k] = transg[(i0 + k) * NTAU + j0];
                tr1[k] = transg[(i0 + k) * NTAU + j0 + 1];
            }
        }
    }

    // ---- reset-slot mapping (r3-proven): thread = (off o, base s); blocks s,s+36,s+72
    const bool ract = (tid < 1008);
    const int ro = ract ? (tid / 36) : 27;
    const int rs = tid % 36;
    const bool rv2 = ract && (rs < 10);
    const int rb0 = rs, rb1 = rs + 36, rb2 = rs + 72;
    const int rt0 = TMIN + rb0, rt1 = TMIN + rb1, rt2 = TMIN + (rv2 ? rb2 : 0);
    const int rf0 = first_of(rb0), rf1 = first_of(rb1), rf2 = rv2 ? first_of(rb2) : 0;
    int rr0 = ro, rr1 = ro, rr2 = ro;

    // ---- non-reset mapping (r3-proven): flat f over 3321, 4 static slots ----
    int nrR[4], nrFo[4], nrTau[4];
    bool nrV[4];
#pragma unroll
    for (int q = 0; q < 4; ++q) {
        const int f = tid + q * NTHREADS;
        nrV[q] = (f < 3321);
        nrR[q] = 0; nrFo[q] = 0; nrTau[q] = 109;
        if (nrV[q]) {
            int lo = 1, hi = NTAU - 1;
            while (lo < hi) { int mid = (lo + hi + 1) >> 1;
                              if (nf_of(mid) <= f) lo = mid; else hi = mid - 1; }
            const int m = f - nf_of(lo);
            nrR[q]   = TMIN + m;
            nrFo[q]  = first_of(lo);
            nrTau[q] = TMIN + lo;
        }
    }

    // ---- V init ----
    const float logS = (float)log((double)S_TOT);
    const float b0 = blp[0], n0 = nblp[0];
    for (int g = tid; g < S_TOT; g += NTHREADS) {
        int lo = 0, hi = NTAU - 1;
        while (lo < hi) { int mid = (lo + hi + 1) >> 1;
                          if (first_of(mid) <= g) lo = mid; else hi = mid - 1; }
        const int tau = TMIN + lo;
        const int r = g - first_of(lo);
        V[g] = ((r == tau - 1) ? b0 : n0) - logS;
    }

    auto winload = [&](int cc) {
        if (cc < NCHUNK && tid < WMAX) {
            int gt = 1 + cc * WMAX + tid;
            win_nb[cc & 3][tid] = (gt < TF) ? nblp[gt] : 0.0f;
            win_b [cc & 3][tid] = (gt < TF) ? blp[gt]  : 0.0f;
        }
    };
    winload(0);
    winload(1);
    __syncthreads();

    float cv0 = 0.0f, cv1 = 0.0f, cv2 = 0.0f;
    for (int c = 0; c < NCHUNK; ++c) {
        const int buf = c & 3;

        // ---- window to registers (b128 loads; constant-index use only) ----
        float nbr[WMAX];
        {
            const float4* wn4 = (const float4*)&win_nb[buf][0];
#pragma unroll
            for (int qq = 0; qq < 7; ++qq) {
                float4 t4 = wn4[qq];
                nbr[4*qq+0] = t4.x; nbr[4*qq+1] = t4.y; nbr[4*qq+2] = t4.z; nbr[4*qq+3] = t4.w;
            }
        }

        // ---- prefix: C = V + nb[0..ro-1]; UNROLLED cndmask on registers ----
        cv0 = ract ? V[rf0 + rr0] : 0.0f;
        cv1 = ract ? V[rf1 + rr1] : 0.0f;
        cv2 = rv2  ? V[rf2 + rr2] : 0.0f;
#pragma unroll
        for (int tt = 0; tt < WMAX; ++tt) {
            const float a = (tt < ro) ? nbr[tt] : 0.0f;   // +0.0 exact
            cv0 += a; cv1 += a; cv2 += a;
        }
        if (ract) {
            A_lds[ro * AP + rb0] = cv0;
            A_lds[ro * AP + rb1] = cv1;
            if (rv2) A_lds[ro * AP + rb2] = cv2;
        }
        winload(c + 2);
        __syncthreads();   // B1: captures ready

        // ---- A history to global (coalesced float4) ----
        if (tid < CHUNK_F / 4) {
            float4 v4 = ((const float4*)A_lds)[tid];
            ((float4*)(Ah + (size_t)c * CHUNK_F))[tid] = v4;
        }

        // ---- ph2: from_beat max-plus; terms paired -> 2 adds + 1 v_max3_f32 ----
        if (p2act) {
#pragma unroll
            for (int u = 0; u < 5; ++u) {
                const int tl = tg + 6 * u;
                if (tl < WMAX) {
                    const float4* ar4 = (const float4*)&A_lds[tl * AP + i0];
                    const float4 a0 = ar4[0], a1 = ar4[1], a2 = ar4[2],
                                 a3 = ar4[3], a4 = ar4[4];
                    float m0 = -INFINITY, m1 = -INFINITY;
#define PH2_STEP2(av, aw, ka, kb) { \
    float x0 = (av) + tr0[ka]; float y0 = (aw) + tr0[kb]; \
    m0 = fmaxf(fmaxf(m0, x0), y0); \
    float x1 = (av) + tr1[ka]; float y1 = (aw) + tr1[kb]; \
    m1 = fmaxf(fmaxf(m1, x1), y1); }
                    PH2_STEP2(a0.x, a0.y, 0, 1)   PH2_STEP2(a0.z, a0.w, 2, 3)
                    PH2_STEP2(a1.x, a1.y, 4, 5)   PH2_STEP2(a1.z, a1.w, 6, 7)
                    PH2_STEP2(a2.x, a2.y, 8, 9)   PH2_STEP2(a2.z, a2.w, 10, 11)
                    PH2_STEP2(a3.x, a3.y, 12, 13) PH2_STEP2(a3.z, a3.w, 14, 15)
                    PH2_STEP2(a4.x, a4.y, 16, 17) PH2_STEP2(a4.z, a4.w, 18, 19)
                    if (iseg == 3) {
                        float a20 = A_lds[tl * AP + 80];
                        float a21 = A_lds[tl * AP + 81];
                        PH2_STEP2(a20, a21, 20, 21)
                    }
#undef PH2_STEP2
                    m0 = fmaxf(m0, __shfl_xor(m0, 1)); m1 = fmaxf(m1, __shfl_xor(m1, 1));
                    m0 = fmaxf(m0, __shfl_xor(m0, 2)); m1 = fmaxf(m1, __shfl_xor(m1, 2));
                    if (iseg == 0) *(float2*)&fb[tl * AP + j0] = make_float2(m0, m1);
                }
            }
        }

        // ---- non-reset slots: 28 sequential adds, slots paired via v_pk_add_f32 --
        {
            const int a0 = nrFo[0] + nrR[0];
            const int a1 = nrFo[1] + nrR[1];
            const int a2 = nrFo[2] + nrR[2];
            const int a3 = nrV[3] ? (nrFo[3] + nrR[3]) : a2;   // alias when absent
            v2f v01 = v2f{V[a0], V[a1]};
            v2f v23 = v2f{V[a2], V[a3]};
#pragma unroll
            for (int tt = 0; tt < WMAX; ++tt) {
                const float w = nbr[tt];
                v01 += v2f{w, w};          // v_pk_add_f32: lanes independent, exact
                v23 += v2f{w, w};
            }
            V[a0] = v01.x; V[a1] = v01.y; V[a2] = v23.x;
            if (nrV[3]) V[a3] = v23.y;
        }
        __syncthreads();   // B2: fb ready

        // ---- suffix: entry + remaining adds; UNROLLED cndmask on registers ----
        {
            const float bw = win_b[buf][ro];
            float e0 = ract ? (fb[ro * AP + rb0] + bw) : 0.0f;
            float e1 = ract ? (fb[ro * AP + rb1] + bw) : 0.0f;
            float e2 = rv2  ? (fb[ro * AP + rb2] + bw) : 0.0f;
#pragma unroll
            for (int tt = 1; tt < WMAX; ++tt) {
                const float a = (tt > ro) ? nbr[tt] : 0.0f;   // +0.0 exact
                e0 += a; e1 += a; e2 += a;
            }
            // last chunk: resets at padded offsets (ro>=7) must not happen;
            // capture C == exact final value there (pad adds are +0.0)
            const bool keepC = (c == NCHUNK - 1) && (ro >= 7);
            if (ract) {
                V[rf0 + rr0] = keepC ? cv0 : e0;
                V[rf1 + rr1] = keepC ? cv1 : e1;
                if (rv2) V[rf2 + rr2] = keepC ? cv2 : e2;
            }
            rr0 += WMAX; if (rr0 >= rt0) rr0 -= rt0;
            rr1 += WMAX; if (rr1 >= rt1) rr1 -= rt1;
            rr2 += WMAX; if (rr2 >= rt2) rr2 -= rt2;
        }
#pragma unroll
        for (int q = 0; q < 4; ++q) {
            if (nrV[q]) { nrR[q] += WMAX; if (nrR[q] >= nrTau[q]) nrR[q] -= nrTau[q]; }
        }
        __syncthreads();   // B3: protect V writes from next chunk's prefix reads
    }

    // ---- final argmax over V (p = (5998 - r) mod tau) ----
    float bvv = -INFINITY; int bss = 0x7fffffff;
    for (int g = tid; g < S_TOT; g += NTHREADS) {
        int lo = 0, hi = NTAU - 1;
        while (lo < hi) { int mid = (lo + hi + 1) >> 1;
                          if (first_of(mid) <= g) lo = mid; else hi = mid - 1; }
        const int tau = TMIN + lo;
        const int r = g - first_of(lo);
        const int p = (5998 - r) % tau;
        const int s = first_of(lo) + p;
        const float v = V[g];
        if (v > bvv || (v == bvv && s < bss)) { bvv = v; bss = s; }
    }
#pragma unroll
    for (int d = 1; d < 64; d <<= 1) {
        float ov = __shfl_xor(bvv, d);
        int   os = __shfl_xor(bss, d);
        if (ov > bvv || (ov == bvv && os < bss)) { bvv = ov; bss = os; }
    }
    if ((tid & 63) == 0) { wv[tid >> 6] = bvv; wi[tid >> 6] = bss; }
    __syncthreads();

    __threadfence();   // Ah global writes visible before backtrace reads

    // ---- backtrace: wave 0, wave-parallel 82-wide argmax per beat boundary ----
    if (tid < 64) {
        const int lane = tid;
        float bvF = (lane < 16) ? wv[lane] : -INFINITY;
        int   bvI = (lane < 16) ? wi[lane] : 0x7fffffff;
#pragma unroll
        for (int d = 1; d < 16; d <<= 1) {
            float ov = __shfl_xor(bvF, d);
            int   os = __shfl_xor(bvI, d);
            if (ov > bvF || (ov == bvF && os < bvI)) { bvF = ov; bvI = os; }
        }
        int s = __shfl(bvI, 0);
        int t = TF - 1;
        for (int guard = 0; guard < 400; ++guard) {
            int lo = 0, hi = NTAU - 1;
            while (lo < hi) { int mid = (lo + hi + 1) >> 1;
                              if (first_of(mid) <= s) lo = mid; else hi = mid - 1; }
            int j = lo;
            int p = s - first_of(j);
            int tb = t - p;
            if (tb < 0) break;
            if (lane == 0) {
                float x = logit[b * TF + tb];
                float act = 1.0f / (1.0f + expf(-x));
                if (act >= 0.05f) out[b * TF + tb] = 1.0f;
            }
            if (tb == 0) break;
            const int tq = tb - 1;
            const float* arow = Ah + (size_t)(tq / WMAX) * CHUNK_F + (tq % WMAX) * AP;
            float cvv = arow[lane] + transg[lane * NTAU + j];
            int ci = lane;
            if (lane < NTAU - 64) {
                float c2 = arow[64 + lane] + transg[(64 + lane) * NTAU + j];
                if (c2 > cvv) { cvv = c2; ci = 64 + lane; }
            }
#pragma unroll
            for (int d = 1; d < 64; d <<= 1) {
                float ov = __shfl_xor(cvv, d, 64);
                int   oi = __shfl_xor(ci, d, 64);
                if (ov > cvv || (ov == cvv && oi < ci)) { cvv = ov; ci = oi; }
            }
            s = first_of(ci) + (TMIN + ci) - 1;   // last_idx[i*]
            t = tb - 1;
        }
    }
}

extern "C" void kernel_launch(void* const* d_in, const int* in_sizes, int n_in,
                              void* d_out, int out_size, void* d_ws, size_t ws_size,
                              hipStream_t stream) {
    const float* logit = (const float*)d_in[0];
    float* out = (float*)d_out;
    float* ws = (float*)d_ws;
    k_trans<<<dim3(NTAU), dim3(128), 0, stream>>>(ws);
    k_emis<<<dim3((BATCH * TF + 255) / 256), dim3(256), 0, stream>>>(logit, ws, out);
    k_viterbi<<<dim3(BATCH), dim3(NTHREADS), 0, stream>>>(
        logit, ws + TRANS_OFF, ws + BLP_OFF, ws + NBLP_OFF, ws + AH_OFF, out);
}

// Round 11
// 1397.993 us; speedup vs baseline: 1.1710x; 1.1710x over previous
//
#include <hip/hip_runtime.h>
#include <math.h>

#define NTAU 82
#define TMIN 28
#define S_TOT 5617
#define TF 6000
#define BATCH 4
#define WMAX 28
#define AP 84            // A/fb row pitch: 82 + 2 pad; rows 336B = 21*16B aligned
#define NTHREADS 1024
#define NCHUNK 215
#define CHUNK_F (WMAX * AP)   // 2352 floats per chunk of A-history
#define NPOS 41          // own tempo blocks per half (block = 2*pos + h)

// ws layout (float offsets)
#define TRANS_OFF 0            // 82*82
#define BLP_OFF   8192         // 4*6000
#define NBLP_OFF  32768        // 4*6000
#define AH_OFF    57344        // 4 * 215 * 2352 (chunk-major A history; also the
                               // cross-half capture exchange buffer — chunk-unique
                               // addresses => no cache-staleness on re-reads)
#define FLAG_OFF  (AH_OFF + BATCH * NCHUNK * CHUNK_F)   // 8 ints (+pad)
#define RESV_OFF  (FLAG_OFF + 16)                       // 8 floats
#define RESI_OFF  (RESV_OFF + 8)                        // 8 ints

typedef float v2f __attribute__((ext_vector_type(2)));

__device__ __forceinline__ int first_of(int b) { return b * (55 + b) / 2; }

__device__ __forceinline__ float logsig(float x) {
    return -(fmaxf(-x, 0.0f) + log1pf(expf(-fabsf(x))));
}

// ---------------- setup kernel 1: trans_log in fp64, cast to fp32 -------------
__global__ void k_trans(float* __restrict__ ws) {
    int i = blockIdx.x;
    int j = threadIdx.x;
    __shared__ double sh[128];
    double raw = 0.0, e = 0.0;
    double ti = 28.0 + (double)i;
    if (j < NTAU) {
        double tj = 28.0 + (double)j;
        raw = -100.0 * fabs(tj / ti - 1.0);
        e = exp(raw);
    }
    sh[j] = e;
    __syncthreads();
    for (int st = 64; st > 0; st >>= 1) {
        if (j < st) sh[j] += sh[j + st];
        __syncthreads();
    }
    double lse = log(sh[0]);
    if (j < NTAU) ws[TRANS_OFF + i * NTAU + j] = (float)(raw - lse);
}

// ---------------- setup kernel 2: emissions + zero output ---------------------
__global__ void k_emis(const float* __restrict__ logit, float* __restrict__ ws,
                       float* __restrict__ out) {
    int idx = blockIdx.x * blockDim.x + threadIdx.x;
    if (idx < BATCH * TF) {
        float x = logit[idx];
        ws[BLP_OFF + idx]  = logsig(x);
        ws[NBLP_OFF + idx] = logsig(-x);
        out[idx] = 0.0f;
    }
}

// ---------------- setup kernel 3: zero the handshake flags --------------------
__global__ void k_flags(int* __restrict__ flags) {
    if (threadIdx.x < 16) flags[threadIdx.x] = 0;
}

// ---------------- main kernel: 2 CUs per batch, split by block parity ---------
__global__ __attribute__((amdgpu_flat_work_group_size(NTHREADS, NTHREADS),
                          amdgpu_waves_per_eu(4, 4),
                          amdgpu_num_vgpr(128)))
void k_viterbi(const float* __restrict__ logit,
               const float* __restrict__ transg,
               const float* __restrict__ blp_all,
               const float* __restrict__ nblp_all,
               float* __restrict__ Ah_all,
               int*   __restrict__ flags,
               float* __restrict__ resv,
               int*   __restrict__ resi,
               float* __restrict__ out) {
    const int tid = threadIdx.x;
    const int b   = blockIdx.x >> 1;   // batch
    const int h   = blockIdx.x & 1;    // half: owns tempo blocks 2*pos + h

    const float* blp  = blp_all  + b * TF;
    const float* nblp = nblp_all + b * TF;
    float* Ah = Ah_all + (size_t)b * (NCHUNK * CHUNK_F);
    int* flagOut = flags + b * 2 + h;
    int* flagIn  = flags + b * 2 + (1 - h);

    __shared__ float V[2832];                       // own slots: idx = fo_own(pos)+r
    __shared__ __align__(16) float A_lds[CHUNK_F];  // full 82-col capture rows
    __shared__ __align__(16) float fb[CHUNK_F];     // from_beat, own cols only
    __shared__ __align__(16) float win_nb[4][WMAX];
    __shared__ __align__(16) float win_b[4][WMAX];
    __shared__ float wv[16];
    __shared__ int   wi[16];
    __shared__ int   sstate;

    // ---- ph2 mapping: quad lanes = iseg; jpp = own j-pair; tg = tl-group(12) ----
    const int iseg = tid & 3;
    const int jpp  = (tid >> 2) % 21;     // own cols j0 = 4*jpp+h, j1 = 4*jpp+2+h
    const int tg   = tid / 84;            // 0..11 (84 = 4*21; quads never straddle)
    const bool p2act = (tid < 1008);
    const int i0 = iseg * 20;             // 20/20/20/22 split; 16B-aligned offsets
    const int j0 = 4 * jpp + h;
    const bool j1v = (jpp < 20);
    const int j1 = j1v ? (4 * jpp + 2 + h) : j0;

    float tr0[22], tr1[22];
#pragma unroll
    for (int k = 0; k < 22; ++k) { tr0[k] = -1.0e30f; tr1[k] = -1.0e30f; }
    if (p2act) {
        const int icnt = (iseg == 3) ? 22 : 20;
#pragma unroll
        for (int k = 0; k < 22; ++k) {
            if (k < icnt) {
                tr0[k] = transg[(i0 + k) * NTAU + j0];
                if (j1v) tr1[k] = transg[(i0 + k) * NTAU + j1];
            }
        }
    }

    // ---- reset mapping: thread = (off o, base sp); own positions sp, sp+36 ----
    const bool ract = (tid < 1008);       // 28*36
    const int ro = ract ? (tid / 36) : 27;
    const int sp = tid % 36;
    const bool rv2 = ract && (sp < 5);    // second position only if sp+36 < 41
    const int pA = sp, pB = sp + 36;
    const int colA = 2 * pA + h, colB = 2 * pB + h;
    const int tauA = 28 + 2 * pA + h, tauB = 28 + 2 * pB + h;
    const int foA = pA * (27 + pA + h), foB = pB * (27 + pB + h);
    int rrA = ro, rrB = ro;

    // ---- non-reset mapping: flat f over own 1640/1681, 2 static slots ----
    const int NF_TOT = NPOS * (NPOS - 1 + h);
    int nrR[2], nrFo[2], nrTau[2];
    bool nrV[2];
#pragma unroll
    for (int q = 0; q < 2; ++q) {
        const int f = tid + q * NTHREADS;
        nrV[q] = (f < NF_TOT);
        nrR[q] = 28; nrFo[q] = 0; nrTau[q] = 109;
        if (nrV[q]) {
            int lo = 0, hi = NPOS - 1;    // largest pos with pos*(pos-1+h) <= f
            while (lo < hi) { int mid = (lo + hi + 1) >> 1;
                              if (mid * (mid - 1 + h) <= f) lo = mid; else hi = mid - 1; }
            const int m = f - lo * (lo - 1 + h);
            nrR[q]   = TMIN + m;
            nrFo[q]  = lo * (27 + lo + h);
            nrTau[q] = TMIN + 2 * lo + h;
        }
    }

    // ---- import mapping (partner cols of Ah chunk rows) ----
    const int ttI0 = tid / 41, psI0 = tid % 41;
    const int offI0 = ttI0 * AP + 2 * psI0 + (1 - h);
    const bool vI1 = (tid < 124);
    const int ttI1 = (tid + 1024) / 41, psI1 = (tid + 1024) % 41;
    const int offI1 = ttI1 * AP + 2 * psI1 + (1 - h);

    // ---- V init (own slots) ----
    const float logS = (float)log((double)S_TOT);
    const float b0 = blp[0], n0 = nblp[0];
    const int SOWN = NPOS * (68 + h);     // 2788 / 2829
    for (int g = tid; g < SOWN; g += NTHREADS) {
        int lo = 0, hi = NPOS - 1;        // largest pos with fo_own(pos) <= g
        while (lo < hi) { int mid = (lo + hi + 1) >> 1;
                          if (mid * (27 + mid + h) <= g) lo = mid; else hi = mid - 1; }
        const int tau = TMIN + 2 * lo + h;
        const int r = g - lo * (27 + lo + h);
        V[g] = ((r == tau - 1) ? b0 : n0) - logS;
    }

    auto winload = [&](int cc) {
        if (cc < NCHUNK && tid < WMAX) {
            int gt = 1 + cc * WMAX + tid;
            win_nb[cc & 3][tid] = (gt < TF) ? nblp[gt] : 0.0f;
            win_b [cc & 3][tid] = (gt < TF) ? blp[gt]  : 0.0f;
        }
    };
    winload(0);
    winload(1);
    __syncthreads();

    float cvA = 0.0f, cvB = 0.0f;
    for (int c = 0; c < NCHUNK; ++c) {
        const int buf = c & 3;
        float* AhC = Ah + (size_t)c * CHUNK_F;

        // window to registers (for non-reset pk chain)
        float nbr[WMAX];
        {
            const float4* wn4 = (const float4*)&win_nb[buf][0];
#pragma unroll
            for (int qq = 0; qq < 7; ++qq) {
                float4 t4 = wn4[qq];
                nbr[4*qq+0] = t4.x; nbr[4*qq+1] = t4.y; nbr[4*qq+2] = t4.z; nbr[4*qq+3] = t4.w;
            }
        }

        // ---- prefix: capture C = V + nb[0..ro-1]; write LDS + publish to Ah ----
        cvA = ract ? V[foA + rrA] : 0.0f;
        cvB = rv2  ? V[foB + rrB] : 0.0f;
        for (int tt = 0; tt < ro; ++tt) {
            const float w = win_nb[buf][tt];
            cvA += w; cvB += w;
        }
        if (ract) {
            A_lds[ro * AP + colA] = cvA;
            AhC[ro * AP + colA]   = cvA;            // direct global publish
            if (rv2) {
                A_lds[ro * AP + colB] = cvB;
                AhC[ro * AP + colB]   = cvB;
            }
        }
        winload(c + 2);
        __syncthreads();   // B1: own captures in LDS; global stores drained

        // release own chunk-c captures to partner
        if (tid == 0)
            __hip_atomic_fetch_add(flagOut, 1, __ATOMIC_RELEASE, __HIP_MEMORY_SCOPE_AGENT);

        // ---- non-reset slots: 28 sequential adds (overlaps flag propagation) ----
        {
            const int a0 = nrFo[0] + nrR[0];
            const int a1 = nrV[1] ? (nrFo[1] + nrR[1]) : a0;
            v2f v01 = v2f{V[a0], V[a1]};
#pragma unroll
            for (int tt = 0; tt < WMAX; ++tt) v01 += v2f{nbr[tt], nbr[tt]};
            V[a0] = v01.x;
            if (nrV[1]) V[a1] = v01.y;
        }

        // ---- acquire partner's chunk-c captures ----
        if (tid == 0) {
            int guard = 0;
            while (__hip_atomic_load(flagIn, __ATOMIC_ACQUIRE, __HIP_MEMORY_SCOPE_AGENT) < c + 1) {
                __builtin_amdgcn_s_sleep(1);
                if (++guard > (1 << 24)) break;   // hang guard -> visible failure
            }
        }
        __syncthreads();   // B2: partner data globally visible

        // ---- import partner cols into A_lds ----
        A_lds[offI0] = AhC[offI0];
        if (vI1) A_lds[offI1] = AhC[offI1];
        __syncthreads();   // B3: full capture rows ready

        // ---- ph2: from_beat for OWN j's; terms paired (2 add + 1 max3) ----
        if (p2act) {
#pragma unroll
            for (int u = 0; u < 3; ++u) {
                const int tl = tg + 12 * u;
                if (tl < WMAX) {
                    const float4* ar4 = (const float4*)&A_lds[tl * AP + i0];
                    const float4 a0 = ar4[0], a1 = ar4[1], a2 = ar4[2],
                                 a3 = ar4[3], a4 = ar4[4];
                    float m0 = -INFINITY, m1 = -INFINITY;
#define PH2_STEP2(av, aw, ka, kb) { \
    float x0 = (av) + tr0[ka]; float y0 = (aw) + tr0[kb]; \
    m0 = fmaxf(fmaxf(m0, x0), y0); \
    float x1 = (av) + tr1[ka]; float y1 = (aw) + tr1[kb]; \
    m1 = fmaxf(fmaxf(m1, x1), y1); }
                    PH2_STEP2(a0.x, a0.y, 0, 1)   PH2_STEP2(a0.z, a0.w, 2, 3)
                    PH2_STEP2(a1.x, a1.y, 4, 5)   PH2_STEP2(a1.z, a1.w, 6, 7)
                    PH2_STEP2(a2.x, a2.y, 8, 9)   PH2_STEP2(a2.z, a2.w, 10, 11)
                    PH2_STEP2(a3.x, a3.y, 12, 13) PH2_STEP2(a3.z, a3.w, 14, 15)
                    PH2_STEP2(a4.x, a4.y, 16, 17) PH2_STEP2(a4.z, a4.w, 18, 19)
                    if (iseg == 3) {
                        float a20 = A_lds[tl * AP + 80];
                        float a21 = A_lds[tl * AP + 81];
                        PH2_STEP2(a20, a21, 20, 21)
                    }
#undef PH2_STEP2
                    m0 = fmaxf(m0, __shfl_xor(m0, 1)); m1 = fmaxf(m1, __shfl_xor(m1, 1));
                    m0 = fmaxf(m0, __shfl_xor(m0, 2)); m1 = fmaxf(m1, __shfl_xor(m1, 2));
                    if (iseg == 0) {
                        fb[tl * AP + j0] = m0;
                        if (j1v) fb[tl * AP + j1] = m1;
                    }
                }
            }
        }
        __syncthreads();   // B4: fb own cols ready

        // ---- suffix: entry + remaining adds (exact sequential) ----
        {
            const float bw = win_b[buf][ro];
            float eA = ract ? (fb[ro * AP + colA] + bw) : 0.0f;
            float eB = rv2  ? (fb[ro * AP + colB] + bw) : 0.0f;
            for (int tt = ro + 1; tt < WMAX; ++tt) {
                const float w = win_nb[buf][tt];
                eA += w; eB += w;
            }
            // last chunk (real width 7): resets at ro>=7 must not happen;
            // capture C == exact final value there (pad adds are +0.0)
            const bool keepC = (c == NCHUNK - 1) && (ro >= 7);
            if (ract) {
                V[foA + rrA] = keepC ? cvA : eA;
                if (rv2) V[foB + rrB] = keepC ? cvB : eB;
            }
            rrA += WMAX; if (rrA >= tauA) rrA -= tauA;
            rrB += WMAX; if (rrB >= tauB) rrB -= tauB;
        }
#pragma unroll
        for (int q = 0; q < 2; ++q) {
            if (nrV[q]) { nrR[q] += WMAX; if (nrR[q] >= nrTau[q]) nrR[q] -= nrTau[q]; }
        }
        __syncthreads();   // B5: protect V writes from next chunk's prefix reads
    }

    // ---- final argmax over OWN V (p = (5998 - r) mod tau; global state idx) ----
    float bvv = -INFINITY; int bss = 0x7fffffff;
    for (int g = tid; g < SOWN; g += NTHREADS) {
        int lo = 0, hi = NPOS - 1;
        while (lo < hi) { int mid = (lo + hi + 1) >> 1;
                          if (mid * (27 + mid + h) <= g) lo = mid; else hi = mid - 1; }
        const int tau = TMIN + 2 * lo + h;
        const int r = g - lo * (27 + lo + h);
        const int p = (5998 - r) % tau;
        const int s = first_of(2 * lo + h) + p;
        const float v = V[g];
        if (v > bvv || (v == bvv && s < bss)) { bvv = v; bss = s; }
    }
#pragma unroll
    for (int d = 1; d < 64; d <<= 1) {
        float ov = __shfl_xor(bvv, d);
        int   os = __shfl_xor(bss, d);
        if (ov > bvv || (ov == bvv && os < bss)) { bvv = ov; bss = os; }
    }
    if ((tid & 63) == 0) { wv[tid >> 6] = bvv; wi[tid >> 6] = bss; }
    __syncthreads();

    if (tid == 0) {
        float bv = wv[0]; int bs = wi[0];
#pragma unroll
        for (int k = 1; k < 16; ++k) {
            if (wv[k] > bv || (wv[k] == bv && wi[k] < bs)) { bv = wv[k]; bs = wi[k]; }
        }
        resv[b * 2 + h] = bv;
        resi[b * 2 + h] = bs;
        // release: covers RES + all residual Ah writes
        __hip_atomic_fetch_add(flagOut, 1, __ATOMIC_RELEASE, __HIP_MEMORY_SCOPE_AGENT);
        wv[0] = bv; wi[0] = bs;
    }
    if (h == 1) return;          // half 1 done; half 0 backtraces
    __syncthreads();

    if (tid == 0) {
        int guard = 0;
        while (__hip_atomic_load(flagIn, __ATOMIC_ACQUIRE, __HIP_MEMORY_SCOPE_AGENT) < NCHUNK + 1) {
            __builtin_amdgcn_s_sleep(1);
            if (++guard > (1 << 26)) break;
        }
        float bv = wv[0]; int bs = wi[0];
        const float pv = resv[b * 2 + 1];
        const int   ps = resi[b * 2 + 1];
        if (pv > bv || (pv == bv && ps < bs)) { bv = pv; bs = ps; }
        sstate = bs;
    }
    __syncthreads();

    // ---- backtrace: wave 0, wave-parallel 82-wide argmax per beat boundary ----
    if (tid < 64) {
        const int lane = tid;
        int s = sstate;
        int t = TF - 1;
        for (int guard = 0; guard < 400; ++guard) {
            int lo = 0, hi = NTAU - 1;
            while (lo < hi) { int mid = (lo + hi + 1) >> 1;
                              if (first_of(mid) <= s) lo = mid; else hi = mid - 1; }
            int j = lo;
            int p = s - first_of(j);
            int tb = t - p;
            if (tb < 0) break;
            if (lane == 0) {
                float x = logit[b * TF + tb];
                float act = 1.0f / (1.0f + expf(-x));
                if (act >= 0.05f) out[b * TF + tb] = 1.0f;
            }
            if (tb == 0) break;
            const int tq = tb - 1;
            const float* arow = Ah + (size_t)(tq / WMAX) * CHUNK_F + (tq % WMAX) * AP;
            float cvv = arow[lane] + transg[lane * NTAU + j];
            int ci = lane;
            if (lane < NTAU - 64) {
                float c2 = arow[64 + lane] + transg[(64 + lane) * NTAU + j];
                if (c2 > cvv) { cvv = c2; ci = 64 + lane; }
            }
#pragma unroll
            for (int d = 1; d < 64; d <<= 1) {
                float ov = __shfl_xor(cvv, d, 64);
                int   oi = __shfl_xor(ci, d, 64);
                if (ov > cvv || (ov == cvv && oi < ci)) { cvv = ov; ci = oi; }
            }
            s = first_of(ci) + (TMIN + ci) - 1;   // last_idx[i*]
            t = tb - 1;
        }
    }
}

extern "C" void kernel_launch(void* const* d_in, const int* in_sizes, int n_in,
                              void* d_out, int out_size, void* d_ws, size_t ws_size,
                              hipStream_t stream) {
    const float* logit = (const float*)d_in[0];
    float* out = (float*)d_out;
    float* ws = (float*)d_ws;
    k_trans<<<dim3(NTAU), dim3(128), 0, stream>>>(ws);
    k_emis<<<dim3((BATCH * TF + 255) / 256), dim3(256), 0, stream>>>(logit, ws, out);
    k_flags<<<dim3(1), dim3(64), 0, stream>>>((int*)(ws + FLAG_OFF));
    k_viterbi<<<dim3(BATCH * 2), dim3(NTHREADS), 0, stream>>>(
        logit, ws + TRANS_OFF, ws + BLP_OFF, ws + NBLP_OFF, ws + AH_OFF,
        (int*)(ws + FLAG_OFF), ws + RESV_OFF, (int*)(ws + RESI_OFF), out);
}